// Round 11
// baseline (788.386 us; speedup 1.0000x reference)
//
#include <hip/hip_runtime.h>

#define N_NODES 50000
#define N_EDGES 800000
#define D_FEAT  64

#define BKT_SHIFT 6
#define NB  782                         // ceil(50000/64) buckets of 64 nodes
#define C_SCAT 8192                     // edges per scatter workgroup
#define NWG_SCAT ((N_EDGES + C_SCAT - 1) / C_SCAT)   // 98

typedef float nfloat2 __attribute__((ext_vector_type(2)));
typedef float nfloat4 __attribute__((ext_vector_type(4)));

// ---------------- workspace layout (bytes) ----------------
// gcnt  : NB ints     @ 0      (bucket histogram; re-zeroed every call)
// gbase : NB+1 ints   @ 3200   (bucket segment bases, read by gather)
// gcur  : NB ints     @ 6400   (reservation cursors, re-init by scan)
// recs  : E nfloat4   @ 9600   {src_as_float, w0, w1, dst_as_float}
#define WS_GCNT  0
#define WS_GBASE 3200
#define WS_GCUR  6400
#define WS_RECS  9600
#define WS_NEEDED (9600ull + (unsigned long long)N_EDGES * 16ull)

// ---- shared helper: exclusive scan of NB(=782) ints with 256 threads ----
__device__ __forceinline__ void scan_nb(const int* __restrict__ cnt,
                                        int* __restrict__ off) {
    __shared__ int wsum2[4];
    const int tid = threadIdx.x, lane = tid & 63, wid = tid >> 6;
    const int i0 = tid * 4;
    int v[4]; int s = 0;
    #pragma unroll
    for (int j = 0; j < 4; ++j) { v[j] = (i0 + j < NB) ? cnt[i0 + j] : 0; s += v[j]; }
    int x = s;
    #pragma unroll
    for (int k = 1; k < 64; k <<= 1) { int t = __shfl_up(x, k, 64); if (lane >= k) x += t; }
    if (lane == 63) wsum2[wid] = x;
    __syncthreads();
    int wpre = 0;
    for (int k = 0; k < wid; ++k) wpre += wsum2[k];
    int pre = wpre + x - s;                       // exclusive prefix of this chunk
    #pragma unroll
    for (int j = 0; j < 4; ++j) { if (i0 + j < NB) off[i0 + j] = pre; pre += v[j]; }
    if (tid == 255) off[NB] = pre;                // grand total
    __syncthreads();
}

// 1) bucket histogram, LDS-staged (196 WGs x 4096 edges)
__global__ __launch_bounds__(256) void hist_bkt(const int* __restrict__ ei,
                                                int* __restrict__ gcnt) {
    __shared__ int cnt[NB];
    const int tid = threadIdx.x;
    for (int i = tid; i < NB; i += 256) cnt[i] = 0;
    __syncthreads();
    const int base = blockIdx.x * 4096;
    #pragma unroll
    for (int k = 0; k < 16; ++k) {
        const int p = base + k * 256 + tid;
        if (p < N_EDGES)
            atomicAdd(&cnt[__builtin_nontemporal_load(ei + N_EDGES + p) >> BKT_SHIFT], 1);
    }
    __syncthreads();
    for (int i = tid; i < NB; i += 256) if (cnt[i]) atomicAdd(&gcnt[i], cnt[i]);
}

// 2) scan bucket counts -> gbase (segment starts) and gcur (cursors)
__global__ __launch_bounds__(256) void scan_bkt(const int* __restrict__ gcnt,
                                                int* __restrict__ gbase,
                                                int* __restrict__ gcur) {
    __shared__ int c[NB];
    __shared__ int o[NB + 1];
    const int tid = threadIdx.x;
    for (int i = tid; i < NB; i += 256) c[i] = gcnt[i];
    __syncthreads();
    scan_nb(c, o);
    for (int i = tid; i < NB; i += 256) { gbase[i] = o[i]; gcur[i] = o[i]; }
    if (tid == 0) gbase[NB] = o[NB];
}

// 3) WG-local LDS counting sort by bucket, then burst-write records:
//    consecutive sorted slots -> consecutive global addresses (full-line merges).
__global__ __launch_bounds__(256) void scatter_bkt(const int* __restrict__ ei,
                                                   const float* __restrict__ w,
                                                   int* __restrict__ gcur,
                                                   nfloat4* __restrict__ recs) {
    __shared__ int cnt[NB];
    __shared__ int off[NB + 1];
    __shared__ int run[NB];
    __shared__ int gpos[NB];
    __shared__ int seid[C_SCAT];
    const int tid  = threadIdx.x;
    const int base = blockIdx.x * C_SCAT;
    const int csz  = min(C_SCAT, N_EDGES - base);

    for (int i = tid; i < NB; i += 256) cnt[i] = 0;
    __syncthreads();
    for (int k = 0; k < C_SCAT / 256; ++k) {
        const int p = k * 256 + tid;
        if (p < csz) atomicAdd(&cnt[ei[N_EDGES + base + p] >> BKT_SHIFT], 1);
    }
    __syncthreads();
    scan_nb(cnt, off);
    for (int i = tid; i < NB; i += 256) run[i] = off[i];
    __syncthreads();
    // reserve one contiguous global range per non-empty bucket
    for (int i = tid; i < NB; i += 256) {
        const int c = off[i + 1] - off[i];
        gpos[i] = c ? atomicAdd(&gcur[i], c) : 0;
    }
    // rank edges into LDS-sorted order (chunk-local ids)
    for (int k = 0; k < C_SCAT / 256; ++k) {
        const int p = k * 256 + tid;
        if (p < csz) {
            const int r = atomicAdd(&run[ei[N_EDGES + base + p] >> BKT_SHIFT], 1);
            seid[r] = p;
        }
    }
    __syncthreads();
    // write records in sorted order: coalesced, line-dense
    for (int k = 0; k < C_SCAT / 256; ++k) {
        const int p = k * 256 + tid;
        if (p < csz) {
            const int e   = base + seid[p];
            const int dst = ei[N_EDGES + e];          // L1/L2-hot re-read
            const int b   = dst >> BKT_SHIFT;
            const nfloat2 wv = *(const nfloat2*)(w + 2 * (size_t)e);
            nfloat4 rec;
            rec.x = __int_as_float(ei[e]);
            rec.y = wv.x;
            rec.z = wv.y;
            rec.w = __int_as_float(dst);
            recs[(size_t)gpos[b] + (p - off[b])] = rec;
        }
    }
}

// 4) one WG per bucket: LDS f32 accumulator (64 nodes x 128), ds_add_f32;
//    records consumed in arbitrary order; coalesced full-line writeout.
__global__ __launch_bounds__(256) void gather_bkt(const float* __restrict__ state,
                                                  const int* __restrict__ gbase,
                                                  const nfloat4* __restrict__ recs,
                                                  float* __restrict__ out) {
    __shared__ float acc[64 * 128];
    const int tid = threadIdx.x, lane = tid & 63, wid = tid >> 6;
    const int b = blockIdx.x;
    const int node0 = b << BKT_SHIFT;
    const size_t plane = (size_t)N_NODES * D_FEAT;

    for (int i = tid; i < 64 * 128; i += 256) acc[i] = 0.f;
    __syncthreads();

    const int j0 = gbase[b], j1 = gbase[b + 1];
    for (int rbase = j0 + wid * 64; rbase < j1; rbase += 256) {
        const int cnt = min(64, j1 - rbase);
        int s_l = 0, dl_l = 0; float wx_l = 0.f, wy_l = 0.f;
        if (lane < cnt) {
            const nfloat4 r = __builtin_nontemporal_load(recs + rbase + lane);
            s_l  = __float_as_int(r.x);
            wx_l = r.y;
            wy_l = r.z;
            dl_l = __float_as_int(r.w) - node0;
        }
        int j = 0;
        for (; j + 8 <= cnt; j += 8) {
            int s[8], dl[8]; float wx[8], wy[8], v0[8], v1[8];
            #pragma unroll
            for (int u = 0; u < 8; ++u) {
                s[u]  = __shfl(s_l,  j + u, 64);
                wx[u] = __shfl(wx_l, j + u, 64);
                wy[u] = __shfl(wy_l, j + u, 64);
                dl[u] = __shfl(dl_l, j + u, 64);
            }
            #pragma unroll
            for (int u = 0; u < 8; ++u) {
                v0[u] = state[(size_t)s[u] * D_FEAT + lane];
                v1[u] = state[plane + (size_t)s[u] * D_FEAT + lane];
            }
            #pragma unroll
            for (int u = 0; u < 8; ++u) {
                atomicAdd(&acc[dl[u] * 128 + lane],      v0[u] * wx[u]);
                atomicAdd(&acc[dl[u] * 128 + 64 + lane], v1[u] * wy[u]);
            }
        }
        for (; j < cnt; ++j) {
            const int   s  = __shfl(s_l,  j, 64);
            const int   dl = __shfl(dl_l, j, 64);
            const float wx = __shfl(wx_l, j, 64);
            const float wy = __shfl(wy_l, j, 64);
            atomicAdd(&acc[dl * 128 + lane],      state[(size_t)s * D_FEAT + lane] * wx);
            atomicAdd(&acc[dl * 128 + 64 + lane], state[plane + (size_t)s * D_FEAT + lane] * wy);
        }
    }
    __syncthreads();

    const int nb = min(64, N_NODES - node0);
    for (int r = wid; r < nb; r += 4) {
        __builtin_nontemporal_store(acc[r * 128 + lane],
                                    out + (size_t)(node0 + r) * D_FEAT + lane);
        __builtin_nontemporal_store(acc[r * 128 + 64 + lane],
                                    out + plane + (size_t)(node0 + r) * D_FEAT + lane);
    }
}

// ---------------- fallback (ws too small): round-1 atomic kernel ----------------
__global__ __launch_bounds__(256) void scatter_add_kernel(
    const float* __restrict__ state, const int* __restrict__ edge_index,
    const float* __restrict__ weight, float* __restrict__ out) {
    const int e = blockIdx.x * 4 + (threadIdx.x >> 6);
    const int d = threadIdx.x & 63;
    if (e >= N_EDGES) return;
    const int src = edge_index[e];
    const int dst = edge_index[N_EDGES + e];
    const float w0 = weight[e * 2 + 0];
    const float w1 = weight[e * 2 + 1];
    const size_t plane = (size_t)N_NODES * D_FEAT;
    const float s0 = state[(size_t)src * D_FEAT + d];
    const float s1 = state[plane + (size_t)src * D_FEAT + d];
    atomicAdd(out + (size_t)dst * D_FEAT + d,         s0 * w0);
    atomicAdd(out + plane + (size_t)dst * D_FEAT + d, s1 * w1);
}

extern "C" void kernel_launch(void* const* d_in, const int* in_sizes, int n_in,
                              void* d_out, int out_size, void* d_ws, size_t ws_size,
                              hipStream_t stream) {
    const float* state      = (const float*)d_in[0];
    const int*   edge_index = (const int*)d_in[1];
    const float* weight     = (const float*)d_in[2];
    float*       out        = (float*)d_out;

    if (ws_size >= WS_NEEDED) {
        char* ws = (char*)d_ws;
        int*     gcnt  = (int*)(ws + WS_GCNT);
        int*     gbase = (int*)(ws + WS_GBASE);
        int*     gcur  = (int*)(ws + WS_GCUR);
        nfloat4* recs  = (nfloat4*)(ws + WS_RECS);

        (void)hipMemsetAsync(gcnt, 0, NB * sizeof(int), stream);

        hipLaunchKernelGGL(hist_bkt, dim3((N_EDGES + 4095) / 4096), dim3(256), 0, stream,
                           edge_index, gcnt);
        hipLaunchKernelGGL(scan_bkt, dim3(1), dim3(256), 0, stream, gcnt, gbase, gcur);
        hipLaunchKernelGGL(scatter_bkt, dim3(NWG_SCAT), dim3(256), 0, stream,
                           edge_index, weight, gcur, recs);
        hipLaunchKernelGGL(gather_bkt, dim3(NB), dim3(256), 0, stream,
                           state, gbase, recs, out);
    } else {
        (void)hipMemsetAsync(out, 0, (size_t)out_size * sizeof(float), stream);
        hipLaunchKernelGGL(scatter_add_kernel, dim3((N_EDGES + 3) / 4), dim3(256), 0, stream,
                           state, edge_index, weight, out);
    }
}

// Round 12
// 129.933 us; speedup vs baseline: 6.0676x; 6.0676x over previous
//
#include <hip/hip_runtime.h>

#define N_NODES 50000
#define N_EDGES 800000
#define D_FEAT  64

#define BKT_SHIFT 6
#define NB  782                          // ceil(50000/64) buckets of 64 nodes
#define C_SCAT 8192
#define NWG_SCAT ((N_EDGES + C_SCAT - 1) / C_SCAT)   // 98
#define CAP 2048                         // max records/bucket for in-place sort
                                         // (mean 1023, sigma 32 -> 2048 is ~32 sigma)

typedef float nfloat2 __attribute__((ext_vector_type(2)));
typedef float nfloat4 __attribute__((ext_vector_type(4)));

// ---------------- workspace layout (bytes) ----------------
// gcnt    : NB ints      @ 0
// gbase   : NB+1 ints    @ 3200
// gcur    : NB ints      @ 6400
// nodeoff : N+1 ints     @ 9600    (per-node CSR starts; -1 = unsorted bucket)
// recs    : E nfloat4    @ 209664  {src_as_float, w0, w1, dst_as_float}
#define WS_GCNT    0
#define WS_GBASE   3200
#define WS_GCUR    6400
#define WS_NOFF    9600
#define WS_RECS    209664
#define WS_NEEDED  (209664ull + (unsigned long long)N_EDGES * 16ull)

// ---- exclusive scan of NB(=782) ints with 256 threads (ends with sync) ----
__device__ __forceinline__ void scan_nb(const int* __restrict__ cnt,
                                        int* __restrict__ off) {
    __shared__ int wsum2[4];
    const int tid = threadIdx.x, lane = tid & 63, wid = tid >> 6;
    const int i0 = tid * 4;
    int v[4]; int s = 0;
    #pragma unroll
    for (int j = 0; j < 4; ++j) { v[j] = (i0 + j < NB) ? cnt[i0 + j] : 0; s += v[j]; }
    int x = s;
    #pragma unroll
    for (int k = 1; k < 64; k <<= 1) { int t = __shfl_up(x, k, 64); if (lane >= k) x += t; }
    if (lane == 63) wsum2[wid] = x;
    __syncthreads();
    int wpre = 0;
    for (int k = 0; k < wid; ++k) wpre += wsum2[k];
    int pre = wpre + x - s;
    #pragma unroll
    for (int j = 0; j < 4; ++j) { if (i0 + j < NB) off[i0 + j] = pre; pre += v[j]; }
    if (tid == 255) off[NB] = pre;
    __syncthreads();
}

// 1) bucket histogram, LDS-staged
__global__ __launch_bounds__(256) void hist_bkt(const int* __restrict__ ei,
                                                int* __restrict__ gcnt) {
    __shared__ int cnt[NB];
    const int tid = threadIdx.x;
    for (int i = tid; i < NB; i += 256) cnt[i] = 0;
    __syncthreads();
    const int base = blockIdx.x * 4096;
    #pragma unroll
    for (int k = 0; k < 16; ++k) {
        const int p = base + k * 256 + tid;
        if (p < N_EDGES)
            atomicAdd(&cnt[__builtin_nontemporal_load(ei + N_EDGES + p) >> BKT_SHIFT], 1);
    }
    __syncthreads();
    for (int i = tid; i < NB; i += 256) if (cnt[i]) atomicAdd(&gcnt[i], cnt[i]);
}

// 2) scan bucket counts -> gbase, gcur; terminator for nodeoff
__global__ __launch_bounds__(256) void scan_bkt(const int* __restrict__ gcnt,
                                                int* __restrict__ gbase,
                                                int* __restrict__ gcur,
                                                int* __restrict__ nodeoff) {
    __shared__ int c[NB];
    __shared__ int o[NB + 1];
    const int tid = threadIdx.x;
    for (int i = tid; i < NB; i += 256) c[i] = gcnt[i];
    __syncthreads();
    scan_nb(c, o);
    for (int i = tid; i < NB; i += 256) { gbase[i] = o[i]; gcur[i] = o[i]; }
    if (tid == 0) { gbase[NB] = o[NB]; nodeoff[N_NODES] = o[NB]; }
}

// 3) WG-local sort by bucket, burst-write records (full-line merges)
__global__ __launch_bounds__(256) void scatter_bkt(const int* __restrict__ ei,
                                                   const float* __restrict__ w,
                                                   int* __restrict__ gcur,
                                                   nfloat4* __restrict__ recs) {
    __shared__ int cnt[NB];
    __shared__ int off[NB + 1];
    __shared__ int run[NB];
    __shared__ int gpos[NB];
    __shared__ int seid[C_SCAT];
    const int tid  = threadIdx.x;
    const int base = blockIdx.x * C_SCAT;
    const int csz  = min(C_SCAT, N_EDGES - base);

    for (int i = tid; i < NB; i += 256) cnt[i] = 0;
    __syncthreads();
    for (int k = 0; k < C_SCAT / 256; ++k) {
        const int p = k * 256 + tid;
        if (p < csz) atomicAdd(&cnt[ei[N_EDGES + base + p] >> BKT_SHIFT], 1);
    }
    __syncthreads();
    scan_nb(cnt, off);
    for (int i = tid; i < NB; i += 256) run[i] = off[i];
    __syncthreads();
    for (int i = tid; i < NB; i += 256) {
        const int c = off[i + 1] - off[i];
        gpos[i] = c ? atomicAdd(&gcur[i], c) : 0;
    }
    for (int k = 0; k < C_SCAT / 256; ++k) {
        const int p = k * 256 + tid;
        if (p < csz) {
            const int r = atomicAdd(&run[ei[N_EDGES + base + p] >> BKT_SHIFT], 1);
            seid[r] = p;
        }
    }
    __syncthreads();
    for (int k = 0; k < C_SCAT / 256; ++k) {
        const int p = k * 256 + tid;
        if (p < csz) {
            const int e   = base + seid[p];
            const int dst = ei[N_EDGES + e];
            const int b   = dst >> BKT_SHIFT;
            const nfloat2 wv = *(const nfloat2*)(w + 2 * (size_t)e);
            nfloat4 rec;
            rec.x = __int_as_float(ei[e]);
            rec.y = wv.x;
            rec.z = wv.y;
            rec.w = __int_as_float(dst);
            recs[(size_t)gpos[b] + (p - off[b])] = rec;
        }
    }
}

// 4) one WG per bucket: in-place per-node sort of the bucket segment
//    (LDS-staged), emit per-node CSR offsets.
__global__ __launch_bounds__(256) void sort_bkt(const int* __restrict__ gbase,
                                                nfloat4* __restrict__ recs,
                                                int* __restrict__ nodeoff) {
    __shared__ nfloat4 srecs[CAP];       // 32 KB
    __shared__ int cnt64[64];
    __shared__ int run64[64];
    const int tid = threadIdx.x;
    const int b = blockIdx.x;
    const int node0 = b << BKT_SHIFT;
    const int j0 = gbase[b], j1 = gbase[b + 1];
    const int cnt = j1 - j0;

    if (cnt > CAP) {                     // unreachable for this input; keep correct
        if (tid < 64 && node0 + tid < N_NODES) nodeoff[node0 + tid] = -1;
        return;
    }
    if (tid < 64) cnt64[tid] = 0;
    __syncthreads();
    for (int p = tid; p < cnt; p += 256) {
        const nfloat4 r = recs[j0 + p];
        srecs[p] = r;
        atomicAdd(&cnt64[__float_as_int(r.w) - node0], 1);
    }
    __syncthreads();
    if (tid < 64) {
        const int v = cnt64[tid];
        int x = v;
        #pragma unroll
        for (int k = 1; k < 64; k <<= 1) { int t = __shfl_up(x, k, 64); if (tid >= k) x += t; }
        const int excl = x - v;
        run64[tid] = excl;
        if (node0 + tid < N_NODES) nodeoff[node0 + tid] = j0 + excl;
    }
    __syncthreads();
    for (int p = tid; p < cnt; p += 256) {
        const int dl = __float_as_int(srecs[p].w) - node0;
        const int rk = atomicAdd(&run64[dl], 1);
        recs[j0 + rk] = srecs[p];        // WG-private 16-32 KB window: L2-merged
    }
}

// 5) one wave per node, register accumulators, x8 unroll (50K waves)
__global__ __launch_bounds__(256) void gather_kernel(const float* __restrict__ state,
                                                     const int* __restrict__ nodeoff,
                                                     const int* __restrict__ gbase,
                                                     const nfloat4* __restrict__ recs,
                                                     float* __restrict__ out) {
    const int n = blockIdx.x * 4 + (threadIdx.x >> 6);
    const int d = threadIdx.x & 63;
    if (n >= N_NODES) return;
    const size_t plane = (size_t)N_NODES * D_FEAT;

    int j0 = nodeoff[n];
    float a0 = 0.f, a1 = 0.f;
    if (j0 < 0) {
        // oversized-bucket slow path (unreachable for this input): filter scan
        const int b = n >> BKT_SHIFT;
        const int jb0 = gbase[b], jb1 = gbase[b + 1];
        for (int j = jb0; j < jb1; ++j) {
            const nfloat4 r = recs[j];
            if (__float_as_int(r.w) == n) {
                const int s = __float_as_int(r.x);
                a0 += state[(size_t)s * D_FEAT + d]         * r.y;
                a1 += state[plane + (size_t)s * D_FEAT + d] * r.z;
            }
        }
    } else {
        int j1 = nodeoff[n + 1];
        if (j1 < 0) j1 = gbase[(n >> BKT_SHIFT) + 1];   // next bucket unsorted
        for (int base = j0; base < j1; base += 64) {
            const int cnt = min(64, j1 - base);
            nfloat4 r = (nfloat4)(0.f);
            if (d < cnt) r = __builtin_nontemporal_load(recs + base + d);

            int j = 0;
            for (; j + 8 <= cnt; j += 8) {
                int   s[8]; float wx[8], wy[8], v0[8], v1[8];
                #pragma unroll
                for (int u = 0; u < 8; ++u) {
                    s[u]  = __shfl(__float_as_int(r.x), j + u, 64);
                    wx[u] = __shfl(r.y, j + u, 64);
                    wy[u] = __shfl(r.z, j + u, 64);
                }
                #pragma unroll
                for (int u = 0; u < 8; ++u) {
                    v0[u] = state[(size_t)s[u] * D_FEAT + d];
                    v1[u] = state[plane + (size_t)s[u] * D_FEAT + d];
                }
                #pragma unroll
                for (int u = 0; u < 8; ++u) {
                    a0 += v0[u] * wx[u];
                    a1 += v1[u] * wy[u];
                }
            }
            for (; j < cnt; ++j) {
                const int   s  = __shfl(__float_as_int(r.x), j, 64);
                const float wx = __shfl(r.y, j, 64);
                const float wy = __shfl(r.z, j, 64);
                a0 += state[(size_t)s * D_FEAT + d]         * wx;
                a1 += state[plane + (size_t)s * D_FEAT + d] * wy;
            }
        }
    }
    __builtin_nontemporal_store(a0, out + (size_t)n * D_FEAT + d);
    __builtin_nontemporal_store(a1, out + plane + (size_t)n * D_FEAT + d);
}

// ---------------- fallback (ws too small): round-1 atomic kernel ----------------
__global__ __launch_bounds__(256) void scatter_add_kernel(
    const float* __restrict__ state, const int* __restrict__ edge_index,
    const float* __restrict__ weight, float* __restrict__ out) {
    const int e = blockIdx.x * 4 + (threadIdx.x >> 6);
    const int d = threadIdx.x & 63;
    if (e >= N_EDGES) return;
    const int src = edge_index[e];
    const int dst = edge_index[N_EDGES + e];
    const float w0 = weight[e * 2 + 0];
    const float w1 = weight[e * 2 + 1];
    const size_t plane = (size_t)N_NODES * D_FEAT;
    const float s0 = state[(size_t)src * D_FEAT + d];
    const float s1 = state[plane + (size_t)src * D_FEAT + d];
    atomicAdd(out + (size_t)dst * D_FEAT + d,         s0 * w0);
    atomicAdd(out + plane + (size_t)dst * D_FEAT + d, s1 * w1);
}

extern "C" void kernel_launch(void* const* d_in, const int* in_sizes, int n_in,
                              void* d_out, int out_size, void* d_ws, size_t ws_size,
                              hipStream_t stream) {
    const float* state      = (const float*)d_in[0];
    const int*   edge_index = (const int*)d_in[1];
    const float* weight     = (const float*)d_in[2];
    float*       out        = (float*)d_out;

    if (ws_size >= WS_NEEDED) {
        char* ws = (char*)d_ws;
        int*     gcnt    = (int*)(ws + WS_GCNT);
        int*     gbase   = (int*)(ws + WS_GBASE);
        int*     gcur    = (int*)(ws + WS_GCUR);
        int*     nodeoff = (int*)(ws + WS_NOFF);
        nfloat4* recs    = (nfloat4*)(ws + WS_RECS);

        (void)hipMemsetAsync(gcnt, 0, NB * sizeof(int), stream);

        hipLaunchKernelGGL(hist_bkt, dim3((N_EDGES + 4095) / 4096), dim3(256), 0, stream,
                           edge_index, gcnt);
        hipLaunchKernelGGL(scan_bkt, dim3(1), dim3(256), 0, stream,
                           gcnt, gbase, gcur, nodeoff);
        hipLaunchKernelGGL(scatter_bkt, dim3(NWG_SCAT), dim3(256), 0, stream,
                           edge_index, weight, gcur, recs);
        hipLaunchKernelGGL(sort_bkt, dim3(NB), dim3(256), 0, stream,
                           gbase, recs, nodeoff);
        hipLaunchKernelGGL(gather_kernel, dim3((N_NODES + 3) / 4), dim3(256), 0, stream,
                           state, nodeoff, gbase, recs, out);
    } else {
        (void)hipMemsetAsync(out, 0, (size_t)out_size * sizeof(float), stream);
        hipLaunchKernelGGL(scatter_add_kernel, dim3((N_EDGES + 3) / 4), dim3(256), 0, stream,
                           state, edge_index, weight, out);
    }
}